// Round 7
// baseline (180.597 us; speedup 1.0000x reference)
//
#include <hip/hip_runtime.h>

typedef __attribute__((ext_vector_type(8))) short bf16x8;
typedef __attribute__((ext_vector_type(4))) float f32x4;

#define C_DIM 256
#define K_CODES 1024
#define HW 1024
#define N_TOK 32768
#define OUT0_ELEMS 8388608
#define MARGIN 2e-3f
#define NSLOT 32

static __device__ __forceinline__ unsigned short f2bf(float f) {
    unsigned u = __float_as_uint(f);
    unsigned r = (u + 0x7FFFu + ((u >> 16) & 1u)) >> 16;
    return (unsigned short)r;
}

// ---------------------------------------------------------------------------
// Bk: per-code |w|^2, numpy-pairwise f32 (unchanged from passing kernel).
// ---------------------------------------------------------------------------
__global__ void bk_kernel(const float* __restrict__ cb, float* __restrict__ Bk) {
#pragma clang fp contract(off)
    int k = blockIdx.x * blockDim.x + threadIdx.x;
    if (k >= K_CODES) return;
    const float* w = cb + k * C_DIM;
    float s[2];
    for (int h = 0; h < 2; ++h) {
        const float* p = w + h * 128;
        float r[8];
        #pragma unroll
        for (int j = 0; j < 8; ++j) { float v = p[j]; r[j] = v * v; }
        for (int i = 8; i < 128; i += 8) {
            #pragma unroll
            for (int j = 0; j < 8; ++j) { float v = p[i + j]; r[j] = r[j] + v * v; }
        }
        s[h] = ((r[0] + r[1]) + (r[2] + r[3])) + ((r[4] + r[5]) + (r[6] + r[7]));
    }
    Bk[k] = s[0] + s[1];
}

// ---------------------------------------------------------------------------
// cb -> bf16 copy [K][C]
// ---------------------------------------------------------------------------
__global__ __launch_bounds__(64) void cbh_kernel(const float* __restrict__ cb,
                                                 unsigned short* __restrict__ cb_h) {
    int k = blockIdx.x, l = threadIdx.x;
    const float4 v = *(const float4*)&cb[k * C_DIM + l * 4];
    ushort4 o;
    o.x = f2bf(v.x); o.y = f2bf(v.y); o.z = f2bf(v.z); o.w = f2bf(v.w);
    *(ushort4*)&cb_h[k * C_DIM + l * 4] = o;
}

// ---------------------------------------------------------------------------
// z prep: NCHW f32 -> z_t f32 [N][C] (in d_out region, overwritten later by
// out_kernel), z_h bf16 [N][C], A[N] = |z|^2 numpy-pairwise.
// ---------------------------------------------------------------------------
__global__ __launch_bounds__(256) void zprep_kernel(const float* __restrict__ z,
        float* __restrict__ z_t, unsigned short* __restrict__ z_h,
        float* __restrict__ A) {
#pragma clang fp contract(off)
    __shared__ float tile[64 * 257];
    const int t = threadIdx.x, blk = blockIdx.x;
    const int b = blk >> 4, hw0 = (blk & 15) * 64, tok0 = blk * 64;
    const size_t zb = (size_t)b * (C_DIM * HW) + hw0;
    for (int i = 0; i < 64; ++i) {
        int pos = i * 256 + t;
        int c = pos >> 6, hw = pos & 63;
        tile[hw * 257 + c] = z[zb + (size_t)c * HW + hw];
    }
    __syncthreads();
    if (t < 64) {
        const float* p0 = &tile[t * 257];
        float s[2];
        for (int h = 0; h < 2; ++h) {
            const float* p = p0 + h * 128;
            float r[8];
            #pragma unroll
            for (int j = 0; j < 8; ++j) { float v = p[j]; r[j] = v * v; }
            for (int i = 8; i < 128; i += 8) {
                #pragma unroll
                for (int j = 0; j < 8; ++j) { float v = p[i + j]; r[j] = r[j] + v * v; }
            }
            s[h] = ((r[0] + r[1]) + (r[2] + r[3])) + ((r[4] + r[5]) + (r[6] + r[7]));
        }
        A[tok0 + t] = s[0] + s[1];
    }
    for (int i = 0; i < 64; ++i) {
        int pos = i * 256 + t;
        int tl = pos >> 8, c = pos & 255;
        float v = tile[tl * 257 + c];
        z_t[(size_t)(tok0 + tl) * 256 + c] = v;
        z_h[(size_t)(tok0 + tl) * 256 + c] = f2bf(v);
    }
}

// ---------------------------------------------------------------------------
// Main: per 64-token block. SINGLE bf16-MFMA sweep, barrier-free k-loop,
// B-fragments straight from L2. Monotone shared threshold (atomicMin on
// float bits) + candidate collect; exact f32 rescore -> idx.
// ---------------------------------------------------------------------------
__global__ __launch_bounds__(256, 2) void vq_main(
        const unsigned short* __restrict__ z_h, const unsigned short* __restrict__ cb_h,
        const float* __restrict__ A, const float* __restrict__ Bk,
        const float* __restrict__ z_t, const float* __restrict__ cb,
        float* __restrict__ out_idx) {
#pragma clang fp contract(off)
    __shared__ unsigned tmin_u[64];
    __shared__ int   cnt[64];
    __shared__ int   ck[64 * NSLOT];
    __shared__ float cd[64 * NSLOT];

    const int tid = threadIdx.x;
    const int w = tid >> 6, l = tid & 63;
    const int lq = l >> 4, lr = l & 15;
    const int tok0 = blockIdx.x * 64;

    if (tid < 64) { tmin_u[tid] = 0x7f7fffffu; cnt[tid] = 0; }

    // hoist A-fragments straight from global: z[rt*16+lr][cs*32+lq*8 ..+8]
    bf16x8 afr[4][8];
    #pragma unroll
    for (int rt = 0; rt < 4; ++rt)
        #pragma unroll
        for (int cs = 0; cs < 8; ++cs)
            afr[rt][cs] = *(const bf16x8*)(z_h + (size_t)(tok0 + rt * 16 + lr) * 256 + (cs * 4 + lq) * 8);

    float A_l[16];
    #pragma unroll
    for (int s = 0; s < 16; ++s)
        A_l[s] = A[tok0 + (s >> 2) * 16 + lq * 4 + (s & 3)];

    __syncthreads();   // tmin/cnt init visible

    for (int kc = 0; kc < 16; ++kc) {
        const int kcode = kc * 64 + w * 16 + lr;       // this lane's code column
        const float bkv = Bk[kcode];
        const unsigned short* bp = cb_h + (size_t)kcode * 256 + lq * 8;
        bf16x8 bfr[8];
        #pragma unroll
        for (int cs = 0; cs < 8; ++cs)
            bfr[cs] = *(const bf16x8*)(bp + cs * 32);

        f32x4 acc[4];
        #pragma unroll
        for (int rt = 0; rt < 4; ++rt) acc[rt] = (f32x4){0.f, 0.f, 0.f, 0.f};
        #pragma unroll
        for (int cs = 0; cs < 8; ++cs) {
            #pragma unroll
            for (int rt = 0; rt < 4; ++rt)
                acc[rt] = __builtin_amdgcn_mfma_f32_16x16x32_bf16(afr[rt][cs], bfr[cs], acc[rt], 0, 0, 0);
        }

        float est[16];
        #pragma unroll
        for (int s = 0; s < 16; ++s)
            est[s] = fmaf(-2.0f, acc[s >> 2][s & 3], A_l[s] + bkv);

        // per-token min over this chunk's 16 codes (butterfly over lr bits),
        // then one LDS atomicMin per token per wave
        #pragma unroll
        for (int s = 0; s < 16; ++s) {
            float v = est[s];
            v = fminf(v, __shfl_xor(v, 1));
            v = fminf(v, __shfl_xor(v, 2));
            v = fminf(v, __shfl_xor(v, 4));
            v = fminf(v, __shfl_xor(v, 8));
            if (lr == 0) {
                int tl = (s >> 2) * 16 + lq * 4 + (s & 3);
                atomicMin(&tmin_u[tl], __float_as_uint(v));
            }
        }
        // collect candidates (threshold only shrinks toward final min -> safe)
        #pragma unroll
        for (int s = 0; s < 16; ++s) {
            int tl = (s >> 2) * 16 + lq * 4 + (s & 3);
            float thr = __uint_as_float(*(volatile unsigned*)&tmin_u[tl]) + MARGIN;
            if (est[s] <= thr) {
                int pos = atomicAdd(&cnt[tl], 1);
                if (pos < NSLOT) ck[tl * NSLOT + pos] = kcode;
            }
        }
    }
    __syncthreads();

    // exact rescore of candidates (identical arithmetic to the passing kernel)
    {
        int tl = tid >> 2;
        int n = min(cnt[tl], NSLOT);
        const float* zr = z_t + (size_t)(tok0 + tl) * 256;
        float Ag = A[tok0 + tl];
        for (int s = tid & 3; s < n; s += 4) {
            int k = ck[tl * NSLOT + s];
            const float* wr = cb + (size_t)k * 256;
            float acc = 0.0f;
            for (int c = 0; c < 256; c += 4) {
                float4 zv = *(const float4*)&zr[c];
                float4 wv = *(const float4*)&wr[c];
                acc = fmaf(zv.x, wv.x, acc);
                acc = fmaf(zv.y, wv.y, acc);
                acc = fmaf(zv.z, wv.z, acc);
                acc = fmaf(zv.w, wv.w, acc);
            }
            cd[tl * NSLOT + s] = fmaf(-2.0f, acc, Ag + Bk[k]);
        }
    }
    __syncthreads();
    if (tid < 64) {
        int n = cnt[tid];
        float bd = 3.4e38f; int bki = 0x7fffffff;
        if (n <= NSLOT) {
            for (int s = 0; s < n; ++s) {
                float d = cd[tid * NSLOT + s]; int k = ck[tid * NSLOT + s];
                if (d < bd || (d == bd && k < bki)) { bd = d; bki = k; }
            }
        } else {
            // overflow fallback (statistically never): exact scan of all codes
            const float* zr = z_t + (size_t)(tok0 + tid) * 256;
            float Ag = A[tok0 + tid];
            for (int k = 0; k < K_CODES; ++k) {
                const float* wr = cb + (size_t)k * 256;
                float acc = 0.0f;
                for (int c = 0; c < 256; c += 4) {
                    float4 zv = *(const float4*)&zr[c];
                    float4 wv = *(const float4*)&wr[c];
                    acc = fmaf(zv.x, wv.x, acc);
                    acc = fmaf(zv.y, wv.y, acc);
                    acc = fmaf(zv.z, wv.z, acc);
                    acc = fmaf(zv.w, wv.w, acc);
                }
                float d = fmaf(-2.0f, acc, Ag + Bk[k]);
                if (d < bd) { bd = d; bki = k; }
            }
        }
        out_idx[tok0 + tid] = (float)bki;
    }
}

// ---------------------------------------------------------------------------
// Output: out0 = z + (w - z) elementwise (NCHW), loss partials.
// ---------------------------------------------------------------------------
__global__ __launch_bounds__(256, 2) void out_kernel(const float* __restrict__ z,
        const float* __restrict__ cb, const float* __restrict__ out_idx_f,
        float* __restrict__ out0, double* __restrict__ lacc) {
#pragma clang fp contract(off)
    __shared__ float wl[64 * 257];
    __shared__ int fi[64];
    __shared__ double red[256];
    const int t = threadIdx.x, blk = blockIdx.x;
    const int b = blk >> 4, hw0 = (blk & 15) * 64;
    const size_t zb = (size_t)b * (C_DIM * HW) + hw0;
    if (t < 64) fi[t] = (int)out_idx_f[blk * 64 + t];
    __syncthreads();
    for (int i = 0; i < 64; ++i) {
        int pos = i * 256 + t;
        int row = pos >> 8, c = pos & 255;
        wl[row * 257 + c] = cb[(size_t)fi[row] * 256 + c];
    }
    __syncthreads();
    double lsum = 0.0;
    for (int i = 0; i < 64; ++i) {
        int pos = i * 256 + t;
        int c = pos >> 6, hw = pos & 63;
        float zv = z[zb + (size_t)c * HW + hw];
        float wv = wl[hw * 257 + c];
        float d = wv - zv;
        out0[zb + (size_t)c * HW + hw] = zv + d;
        float q = d * d;
        lsum += (double)q;
    }
    red[t] = lsum;
    __syncthreads();
    if (t == 0) {
        double s = 0.0;
        for (int i = 0; i < 256; ++i) s += red[i];
        atomicAdd(lacc, s);
    }
}

__global__ void loss_kernel(const double* __restrict__ acc, float* __restrict__ out_loss) {
    double mse = acc[0] / (double)OUT0_ELEMS;
    out_loss[0] = (float)(mse + 0.25 * mse);
}

extern "C" void kernel_launch(void* const* d_in, const int* in_sizes, int n_in,
                              void* d_out, int out_size, void* d_ws, size_t ws_size,
                              hipStream_t stream) {
    const float* z  = (const float*)d_in[0];
    const float* cb = (const float*)d_in[1];
    float* out      = (float*)d_out;
    float* out_idx  = out + OUT0_ELEMS;
    float* out_loss = out + OUT0_ELEMS + N_TOK;

    char* wsb = (char*)d_ws;
    double*         lacc = (double*)wsb;                       // 64 B
    float*          Bk   = (float*)(wsb + 64);                 // 4 KB
    float*          A    = (float*)(wsb + 8192);               // 128 KB
    unsigned short* cb_h = (unsigned short*)(wsb + 262144);    // 512 KB
    unsigned short* z_h  = (unsigned short*)(wsb + 1048576);   // 16 MB
    float*          z_t  = out;  // reuse out0 region as [N][C] f32 scratch

    hipMemsetAsync(d_ws, 0, 64, stream);
    zprep_kernel<<<512, 256, 0, stream>>>(z, z_t, z_h, A);
    bk_kernel<<<4, 256, 0, stream>>>(cb, Bk);
    cbh_kernel<<<1024, 64, 0, stream>>>(cb, cb_h);
    vq_main<<<512, 256, 0, stream>>>(z_h, cb_h, A, Bk, z_t, cb, out_idx);
    out_kernel<<<512, 256, 0, stream>>>(z, cb, out_idx, out, lacc);
    loss_kernel<<<1, 1, 0, stream>>>(lacc, out_loss);
}